// Round 13
// baseline (524.068 us; speedup 1.0000x reference)
//
#include <hip/hip_runtime.h>

#define NNODES 100000
#define NEDGES 1600000
#define ET (NEDGES + NNODES)      // 1,700,000 incl. self loops
#define NBUCK 782                 // ceil(100000/128) buckets of 128 nodes
#define NEG 0.2f
#define BNEPS 1e-5f
#define EPB 4096                  // edges per block, bucket passes
#define NBLK_E ((ET + EPB - 1) / EPB)   // 416
#define CAP 4096                  // fixed bucket capacity (mean 2174, ~41 sigma)
#define NSLOT 16                  // BN partial-sum slots (contention 12500/16)

typedef __attribute__((ext_vector_type(8))) short short8;
typedef __attribute__((ext_vector_type(4))) float floatx4;
typedef __attribute__((ext_vector_type(2))) float floatx2;

__device__ __forceinline__ unsigned short f2b(float x) {
    unsigned int u = __float_as_uint(x);
    u += 0x7fff + ((u >> 16) & 1);        // RNE
    return (unsigned short)(u >> 16);
}
__device__ __forceinline__ float b2f(unsigned short u) {
    return __uint_as_float(((unsigned int)u) << 16);
}
__device__ __forceinline__ float blo2f(unsigned int v) {
    return __uint_as_float(v << 16);
}
__device__ __forceinline__ float bhi2f(unsigned int v) {
    return __uint_as_float(v & 0xffff0000u);
}
__device__ __forceinline__ floatx2 u2f2(unsigned int v) {
    floatx2 r;
    r.x = __uint_as_float(v << 16);
    r.y = __uint_as_float(v & 0xffff0000u);
    return r;
}

// ---------------- edge decode (int32 vs int64 hedge) ----------------
__device__ __forceinline__ int edge_src(const int* ei, int e, int w64) {
    if (e >= NEDGES) return e - NEDGES;          // self loop
    return w64 ? ei[2 * e] : ei[e];
}
__device__ __forceinline__ int edge_dst(const int* ei, int e, int w64) {
    if (e >= NEDGES) return e - NEDGES;
    return w64 ? ei[2 * (NEDGES + e)] : ei[NEDGES + e];
}

// ---------------- prep: dtype detect + W transposes + cursor/partials init -------
// Also builds split-bf16 Wout^T (WoT1 = bf16(w), WoT2 = bf16(w - WoT1)) padded
// to 48 cols so the head can run on MFMA without precision loss.
__global__ void k_prep(const float* __restrict__ W1, const float* __restrict__ W2,
                       const float* __restrict__ Wout,
                       unsigned short* __restrict__ WT1, unsigned short* __restrict__ WT2,
                       unsigned short* __restrict__ WoT1, unsigned short* __restrict__ WoT2,
                       const int* ei, int* flag, int* bcur, float* gpart) {
    int t = blockIdx.x * 256 + threadIdx.x;      // 16384 threads
    if (t < 800) bcur[t] = t * CAP;
    if (t < 2 * NSLOT * 256) gpart[t] = 0.f;     // 8192 floats (2 layers x 16 x 256)
    if (t == 1) {
        int is64 = 1;
        for (int j = 1; j < 16; j += 2)
            if (ei[j] != 0) is64 = 0;
        *flag = is64;
    }
    if (t < 6144) {                               // WoutT split: [48][128]
        int j = t >> 7, k = t & 127;
        float wv = (j < 40) ? Wout[k * 40 + j] : 0.f;
        unsigned short w1 = f2b(wv);
        WoT1[t] = w1;
        WoT2[t] = f2b(wv - b2f(w1));
    }
    int k = t >> 7, n = t & 127;
    WT1[n * 128 + k] = f2b(W1[t]);
    WT2[n * 128 + k] = f2b(W2[t]);
}

// ---------------- scatter: partition packed pairs into fixed bucket regions ------
__global__ __launch_bounds__(256) void k_bscatter(const int* __restrict__ ei,
                                                  const int* flag, int* bcur,
                                                  int* __restrict__ pairs) {
    __shared__ int lc[784];
    __shared__ int lbase[784];
    int t = threadIdx.x;
    for (int i = t; i < NBUCK; i += 256) lc[i] = 0;
    __syncthreads();
    int w64 = *flag;
    int base = blockIdx.x * EPB;
    for (int j = 0; j < EPB / 512; j++) {
        int e = base + j * 512 + t * 2;
        if (e + 1 < NEDGES) {
            int d0, d1;
            if (w64) {
                int4 dv = *(const int4*)&ei[2 * (NEDGES + e)];
                d0 = dv.x; d1 = dv.z;
            } else {
                int2 dv = *(const int2*)&ei[NEDGES + e];
                d0 = dv.x; d1 = dv.y;
            }
            atomicAdd(&lc[d0 >> 7], 1);
            atomicAdd(&lc[d1 >> 7], 1);
        } else {
            for (int k = 0; k < 2; k++) {
                int ee = e + k;
                if (ee < ET) atomicAdd(&lc[edge_dst(ei, ee, w64) >> 7], 1);
            }
        }
    }
    __syncthreads();
    for (int i = t; i < NBUCK; i += 256)
        if (lc[i]) lbase[i] = atomicAdd(&bcur[i], lc[i]);
    __syncthreads();
    for (int j = 0; j < EPB / 512; j++) {
        int e = base + j * 512 + t * 2;
        if (e + 1 < NEDGES) {
            int s0, s1, d0, d1;
            if (w64) {
                int4 sv = *(const int4*)&ei[2 * e];
                int4 dv = *(const int4*)&ei[2 * (NEDGES + e)];
                s0 = sv.x; s1 = sv.z; d0 = dv.x; d1 = dv.z;
            } else {
                int2 sv = *(const int2*)&ei[e];
                int2 dv = *(const int2*)&ei[NEDGES + e];
                s0 = sv.x; s1 = sv.y; d0 = dv.x; d1 = dv.y;
            }
            int p0 = atomicAdd(&lbase[d0 >> 7], 1);
            pairs[p0] = (s0 << 7) | (d0 & 127);
            int p1 = atomicAdd(&lbase[d1 >> 7], 1);
            pairs[p1] = (s1 << 7) | (d1 & 127);
        } else {
            for (int k = 0; k < 2; k++) {
                int ee = e + k;
                if (ee < ET) {
                    int src = edge_src(ei, ee, w64);
                    int dst = edge_dst(ei, ee, w64);
                    int pos = atomicAdd(&lbase[dst >> 7], 1);
                    pairs[pos] = (src << 7) | (dst & 127);
                }
            }
        }
    }
}

// ---------------- per-bucket counting sort -> rowse (start,end) + srcs ----------
__global__ __launch_bounds__(256) void k_bsort(const int* __restrict__ pairs,
                                               const int* __restrict__ bcur,
                                               int2* __restrict__ rowse,
                                               int* __restrict__ srcs) {
    __shared__ int ncnt[128];
    __shared__ int nbase[128];
    __shared__ int sscan[128];
    int b = blockIdx.x, t = threadIdx.x;
    if (t < 128) ncnt[t] = 0;
    __syncthreads();
    int s0 = b * CAP, s1 = bcur[b];
    for (int i = s0 + t; i < s1; i += 256)
        atomicAdd(&ncnt[pairs[i] & 127], 1);
    __syncthreads();
    int v = (t < 128) ? ncnt[t] : 0;
    if (t < 128) sscan[t] = v;
    __syncthreads();
    for (int off = 1; off < 128; off <<= 1) {
        int add = (t < 128 && t >= off) ? sscan[t - off] : 0;
        __syncthreads();
        if (t < 128) sscan[t] += add;
        __syncthreads();
    }
    if (t < 128) {
        int excl = sscan[t] - v;
        nbase[t] = excl;
        int node = b * 128 + t;
        if (node < NNODES) rowse[node] = make_int2(s0 + excl, s0 + excl + v);
    }
    __syncthreads();
    if (t < 128) ncnt[t] = nbase[t];   // cursor
    __syncthreads();
    for (int i = s0 + t; i < s1; i += 256) {
        int pr = pairs[i];
        int off = atomicAdd(&ncnt[pr & 127], 1);
        srcs[s0 + off] = ((unsigned int)pr) >> 7;
    }
}

// ---------------- MFMA GEMM, 128-row tile (+BN/ELU on bf16 A) + fused scores --------
// BN=true reads the 16-slot BN partials (accumulated by k_attn) instead of a
// separate bnstats pass.
template<bool BN>
__global__ __launch_bounds__(256) void k_gemm(const void* __restrict__ Ain,
        const unsigned short* __restrict__ WTg,
        const float* __restrict__ gpart,
        const float* __restrict__ gamma, const float* __restrict__ beta,
        const float* __restrict__ a_s, const float* __restrict__ a_d,
        float* __restrict__ es, float* __restrict__ ed,
        unsigned short* __restrict__ hB, int n) {
    __shared__ unsigned short lA[128][136];
    __shared__ unsigned short lW[128][136];
    __shared__ float las[128], lad[128];
    __shared__ float lsc[128], lsh[128];
    int t = threadIdx.x;
    int row0 = blockIdx.x * 128;
    if (t < 128) { las[t] = a_s[t]; lad[t] = a_d[t]; }
    if (BN && t < 128) {
        float s = 0.f, q = 0.f;
#pragma unroll
        for (int si = 0; si < NSLOT; si++) {
            s += gpart[si * 256 + t];
            q += gpart[si * 256 + 128 + t];
        }
        float mu = s * (1.f / NNODES);
        float var = fmaxf(q * (1.f / NNODES) - mu * mu, 0.f);
        float sc = gamma[t] * rsqrtf(var + BNEPS);
        lsc[t] = sc;
        lsh[t] = beta[t] - mu * sc;
    }

    const uint4* wt4 = (const uint4*)WTg;
#pragma unroll
    for (int j = 0; j < 8; j++) {
        int idx = t + j * 256;
        *(uint4*)&lW[idx >> 4][(idx & 15) * 8] = wt4[idx];
    }
    if (BN) __syncthreads();   // lsc/lsh visible before A staging

    if (BN) {
        const uint4* Ab = (const uint4*)Ain;   // bf16 rows, 16 uint4 each
#pragma unroll
        for (int j = 0; j < 8; j++) {
            int idx = t + j * 256;             // 2048 uint4 = 128 rows
            int r = idx >> 4, seg = idx & 15;
            uint4 v = make_uint4(0, 0, 0, 0);
            if (row0 + r < n) v = Ab[(size_t)(row0 + r) * 16 + seg];
            float f[8];
            f[0] = blo2f(v.x); f[1] = bhi2f(v.x);
            f[2] = blo2f(v.y); f[3] = bhi2f(v.y);
            f[4] = blo2f(v.z); f[5] = bhi2f(v.z);
            f[6] = blo2f(v.w); f[7] = bhi2f(v.w);
            unsigned short us[8];
#pragma unroll
            for (int k = 0; k < 8; k++) {
                int c = seg * 8 + k;
                float z = fmaf(f[k], lsc[c], lsh[c]);
                z = z > 0.f ? z : __expf(z) - 1.f;
                us[k] = f2b(z);
            }
            ushort4 u0, u1;
            u0.x = us[0]; u0.y = us[1]; u0.z = us[2]; u0.w = us[3];
            u1.x = us[4]; u1.y = us[5]; u1.z = us[6]; u1.w = us[7];
            *(ushort4*)&lA[r][seg * 8] = u0;
            *(ushort4*)&lA[r][seg * 8 + 4] = u1;
        }
    } else {
        const float* Af = (const float*)Ain;
#pragma unroll
        for (int j = 0; j < 16; j++) {
            int idx = t + j * 256;             // 4096 float4 = 128 rows
            int r = idx >> 5, c4 = idx & 31;
            float4 v = make_float4(0.f, 0.f, 0.f, 0.f);
            if (row0 + r < n) v = ((const float4*)Af)[(size_t)(row0 + r) * 32 + c4];
            ushort4 u;
            u.x = f2b(v.x); u.y = f2b(v.y); u.z = f2b(v.z); u.w = f2b(v.w);
            *(ushort4*)&lA[r][c4 * 4] = u;
        }
    }
    __syncthreads();

    int w = t >> 6, lane = t & 63;
    int m = lane & 15, q = lane >> 4;
    int ar0 = w * 32 + m, ar1 = w * 32 + 16 + m;   // two 16-row tiles per wave
    floatx4 acc0[8], acc1[8];
#pragma unroll
    for (int ct = 0; ct < 8; ct++) { acc0[ct] = (floatx4)0.0f; acc1[ct] = (floatx4)0.0f; }

#pragma unroll
    for (int kt = 0; kt < 4; kt++) {
        int kb = kt * 32 + q * 8;
        short8 af0 = *(const short8*)&lA[ar0][kb];
        short8 af1 = *(const short8*)&lA[ar1][kb];
#pragma unroll
        for (int ct = 0; ct < 8; ct++) {
            short8 bf = *(const short8*)&lW[ct * 16 + m][kb];
            acc0[ct] = __builtin_amdgcn_mfma_f32_16x16x32_bf16(af0, bf, acc0[ct], 0, 0, 0);
            acc1[ct] = __builtin_amdgcn_mfma_f32_16x16x32_bf16(af1, bf, acc1[ct], 0, 0, 0);
        }
    }

    __syncthreads();   // all waves done with lA/lW as inputs
#pragma unroll
    for (int ct = 0; ct < 8; ct++)
#pragma unroll
        for (int r = 0; r < 4; r++) {
            lA[w * 32 + q * 4 + r][ct * 16 + m] = f2b(acc0[ct][r]);
            lA[w * 32 + 16 + q * 4 + r][ct * 16 + m] = f2b(acc1[ct][r]);
        }
    __syncthreads();
#pragma unroll
    for (int j = 0; j < 8; j++) {
        int idx = t + j * 256;                 // 2048 uint4 stores
        int r = idx >> 4, seg = idx & 15;
        int grow = row0 + r;
        if (grow < n) {
            uint4 v = *(const uint4*)&lA[r][seg * 8];
            ((uint4*)hB)[(size_t)grow * 16 + seg] = v;
        }
    }
    // fused attention scores: 2 threads per row, 64 chans each (dword LDS reads)
    int r = t >> 1, q2 = t & 1;
    float s1 = 0.f, s2 = 0.f;
#pragma unroll
    for (int k = 0; k < 32; k++) {
        int c = q2 * 64 + 2 * k;
        unsigned int u = *(const unsigned int*)&lA[r][c];
        float va = blo2f(u), vb = bhi2f(u);
        s1 += va * las[c] + vb * las[c + 1];
        s2 += va * lad[c] + vb * lad[c + 1];
    }
    s1 += __shfl_xor(s1, 1, 64);
    s2 += __shfl_xor(s2, 1, 64);
    if (q2 == 0 && row0 + r < n) { es[row0 + r] = s1; ed[row0 + r] = s2; }
}

// ---------------- fused softmax + weighted gather + BN partial sums ----------
// (src, p) staged per half-wave in LDS; FP order identical to prior rounds.
// NEW: per-block BN stats (sum, sumsq of the bf16 outputs) accumulated in LDS
// and flushed to one of NSLOT global partial slots -- replaces k_bnstats.
__global__ __launch_bounds__(256) void k_attn(const unsigned short* __restrict__ hB,
                                              const int* __restrict__ srcs,
                                              const int2* __restrict__ rowse,
                                              const float* __restrict__ es,
                                              const float* __restrict__ ed,
                                              const float* __restrict__ bias,
                                              unsigned short* __restrict__ haggB,
                                              float* __restrict__ gpart, int n) {
    __shared__ uint2 sp[8][32];                      // per half-wave (src, p) stage
    __shared__ float bsum[128], bsqs[128];
    int t = threadIdx.x;
    if (t < 128) { bsum[t] = 0.f; bsqs[t] = 0.f; }
    __syncthreads();
    int w = (blockIdx.x * 256 + t) >> 5;             // node per half-wave
    bool active = (w < n);
    int hw = t >> 5;                                 // half-wave slot in block
    int lane32 = t & 31;
    int g = lane32 >> 4, l16 = lane32 & 15;
    int start = 0, end = 0;
    float edv = 0.f;
    if (active) {
        int2 se = rowse[w];
        start = se.x; end = se.y;
        edv = ed[w];
    }
    const uint4* hp4 = (const uint4*)hB;
    floatx2 a0 = {0.f, 0.f}, a1 = {0.f, 0.f}, a2 = {0.f, 0.f}, a3 = {0.f, 0.f};
    float den = 0.f;

    for (int chunk = start; chunk < end; chunk += 32) {
        int i = chunk + lane32;
        int sv = 0; float pv = 0.f;
        if (i < end) {
            sv = srcs[i];
            float e = es[sv] + edv;
            e = e > 0.f ? e : NEG * e;
            pv = __expf(e);
            den += pv;
        }
        sp[hw][lane32] = make_uint2((unsigned)sv, __float_as_uint(pv));
        int cnt = min(32, end - chunk);
        for (int j = 0; j < cnt; j += 8) {           // group g: edges j+g, j+2+g, ...
            uint2 e0 = sp[hw][j + g];
            uint2 e1 = sp[hw][j + 2 + g];
            uint2 e2 = sp[hw][j + 4 + g];
            uint2 e3 = sp[hw][j + 6 + g];
            uint4 h0 = hp4[e0.x * 16u + l16];
            uint4 h1 = hp4[e1.x * 16u + l16];
            uint4 h2 = hp4[e2.x * 16u + l16];
            uint4 h3 = hp4[e3.x * 16u + l16];
            float p0 = __uint_as_float(e0.y), p1 = __uint_as_float(e1.y);
            float p2 = __uint_as_float(e2.y), p3 = __uint_as_float(e3.y);
            floatx2 P0 = {p0, p0};
            a0 += P0 * u2f2(h0.x); a1 += P0 * u2f2(h0.y);
            a2 += P0 * u2f2(h0.z); a3 += P0 * u2f2(h0.w);
            floatx2 P1 = {p1, p1};
            a0 += P1 * u2f2(h1.x); a1 += P1 * u2f2(h1.y);
            a2 += P1 * u2f2(h1.z); a3 += P1 * u2f2(h1.w);
            floatx2 P2 = {p2, p2};
            a0 += P2 * u2f2(h2.x); a1 += P2 * u2f2(h2.y);
            a2 += P2 * u2f2(h2.z); a3 += P2 * u2f2(h2.w);
            floatx2 P3 = {p3, p3};
            a0 += P3 * u2f2(h3.x); a1 += P3 * u2f2(h3.y);
            a2 += P3 * u2f2(h3.z); a3 += P3 * u2f2(h3.w);
        }
    }
    den += __shfl_xor(den, 1, 64);  den += __shfl_xor(den, 2, 64);
    den += __shfl_xor(den, 4, 64);  den += __shfl_xor(den, 8, 64);
    den += __shfl_xor(den, 16, 64);
    a0.x += __shfl_xor(a0.x, 16, 64); a0.y += __shfl_xor(a0.y, 16, 64);
    a1.x += __shfl_xor(a1.x, 16, 64); a1.y += __shfl_xor(a1.y, 16, 64);
    a2.x += __shfl_xor(a2.x, 16, 64); a2.y += __shfl_xor(a2.y, 16, 64);
    a3.x += __shfl_xor(a3.x, 16, 64); a3.y += __shfl_xor(a3.y, 16, 64);
    if (g == 0 && active) {
        float inv = 1.f / den;                       // den > 0: self loop guaranteed
        const float2* b2p = (const float2*)bias;
        float2 c0 = b2p[l16 * 4 + 0], c1 = b2p[l16 * 4 + 1];
        float2 c2 = b2p[l16 * 4 + 2], c3 = b2p[l16 * 4 + 3];
        uint4 o;
        o.x = (unsigned int)f2b(fmaf(a0.x, inv, c0.x)) |
              ((unsigned int)f2b(fmaf(a0.y, inv, c0.y)) << 16);
        o.y = (unsigned int)f2b(fmaf(a1.x, inv, c1.x)) |
              ((unsigned int)f2b(fmaf(a1.y, inv, c1.y)) << 16);
        o.z = (unsigned int)f2b(fmaf(a2.x, inv, c2.x)) |
              ((unsigned int)f2b(fmaf(a2.y, inv, c2.y)) << 16);
        o.w = (unsigned int)f2b(fmaf(a3.x, inv, c3.x)) |
              ((unsigned int)f2b(fmaf(a3.y, inv, c3.y)) << 16);
        ((uint4*)haggB)[(size_t)w * 16 + l16] = o;
        // BN partials on the rounded bf16 values (matches old bnstats input)
        int cb = l16 * 8;
        float v0 = blo2f(o.x), v1 = bhi2f(o.x);
        float v2 = blo2f(o.y), v3 = bhi2f(o.y);
        float v4 = blo2f(o.z), v5 = bhi2f(o.z);
        float v6 = blo2f(o.w), v7 = bhi2f(o.w);
        atomicAdd(&bsum[cb + 0], v0); atomicAdd(&bsqs[cb + 0], v0 * v0);
        atomicAdd(&bsum[cb + 1], v1); atomicAdd(&bsqs[cb + 1], v1 * v1);
        atomicAdd(&bsum[cb + 2], v2); atomicAdd(&bsqs[cb + 2], v2 * v2);
        atomicAdd(&bsum[cb + 3], v3); atomicAdd(&bsqs[cb + 3], v3 * v3);
        atomicAdd(&bsum[cb + 4], v4); atomicAdd(&bsqs[cb + 4], v4 * v4);
        atomicAdd(&bsum[cb + 5], v5); atomicAdd(&bsqs[cb + 5], v5 * v5);
        atomicAdd(&bsum[cb + 6], v6); atomicAdd(&bsqs[cb + 6], v6 * v6);
        atomicAdd(&bsum[cb + 7], v7); atomicAdd(&bsqs[cb + 7], v7 * v7);
    }
    __syncthreads();
    int slot = (blockIdx.x & (NSLOT - 1)) * 256;
    if (t < 128) atomicAdd(&gpart[slot + t], bsum[t]);
    else         atomicAdd(&gpart[slot + t], bsqs[t - 128]);
}

// ---------------- output head: MFMA GEMM, split-bf16 A and W (fp32-exact) ------
// C[128 x 48] = H[128 x 128] @ WoutT^T; cols 40..47 padded zero. A is BN/ELU'd
// h split into b1 + b2 bf16 tiles; W split into WoT1 + WoT2. Three MFMA passes
// (b1W1 + b2W1 + b1W2) recover fp32 accuracy (residual ~2^-17). Epilogue stages
// fp32 rows in LDS (aliasing lA1) then copies linearly.
__global__ __launch_bounds__(256) void k_outgemm(const unsigned short* __restrict__ h,
                                                 const float* __restrict__ gpart,
                                                 const float* __restrict__ gamma,
                                                 const float* __restrict__ beta,
                                                 const unsigned short* __restrict__ WoT1,
                                                 const unsigned short* __restrict__ WoT2,
                                                 const float* __restrict__ bout,
                                                 float* __restrict__ out, int n) {
    __shared__ unsigned short lA1[128][136];
    __shared__ unsigned short lA2[128][136];
    __shared__ float lsc[128], lsh[128];
    __shared__ float lb[48];
    int t = threadIdx.x;
    if (t < 128) {
        float s = 0.f, q = 0.f;
#pragma unroll
        for (int si = 0; si < NSLOT; si++) {
            s += gpart[si * 256 + t];
            q += gpart[si * 256 + 128 + t];
        }
        float mu = s * (1.f / NNODES);
        float var = fmaxf(q * (1.f / NNODES) - mu * mu, 0.f);
        float sc = gamma[t] * rsqrtf(var + BNEPS);
        lsc[t] = sc;
        lsh[t] = beta[t] - mu * sc;
    }
    if (t >= 128 && t < 176) lb[t - 128] = (t < 168) ? bout[t - 128] : 0.f;
    __syncthreads();
    int row0 = blockIdx.x * 128;
    const uint4* Ab = (const uint4*)h;
#pragma unroll
    for (int j = 0; j < 8; j++) {
        int idx = t + j * 256;                 // 2048 uint4 = 128 rows
        int r = idx >> 4, seg = idx & 15;
        uint4 v = make_uint4(0, 0, 0, 0);
        if (row0 + r < n) v = Ab[(size_t)(row0 + r) * 16 + seg];
        float f[8];
        f[0] = blo2f(v.x); f[1] = bhi2f(v.x);
        f[2] = blo2f(v.y); f[3] = bhi2f(v.y);
        f[4] = blo2f(v.z); f[5] = bhi2f(v.z);
        f[6] = blo2f(v.w); f[7] = bhi2f(v.w);
        unsigned short u1[8], u2[8];
#pragma unroll
        for (int k = 0; k < 8; k++) {
            int c = seg * 8 + k;
            float z = fmaf(f[k], lsc[c], lsh[c]);
            z = z > 0.f ? z : __expf(z) - 1.f;
            unsigned short b1 = f2b(z);
            u1[k] = b1;
            u2[k] = f2b(z - b2f(b1));
        }
        ushort4 a, b;
        a.x = u1[0]; a.y = u1[1]; a.z = u1[2]; a.w = u1[3];
        b.x = u1[4]; b.y = u1[5]; b.z = u1[6]; b.w = u1[7];
        *(ushort4*)&lA1[r][seg * 8] = a;
        *(ushort4*)&lA1[r][seg * 8 + 4] = b;
        a.x = u2[0]; a.y = u2[1]; a.z = u2[2]; a.w = u2[3];
        b.x = u2[4]; b.y = u2[5]; b.z = u2[6]; b.w = u2[7];
        *(ushort4*)&lA2[r][seg * 8] = a;
        *(ushort4*)&lA2[r][seg * 8 + 4] = b;
    }
    __syncthreads();

    int w = t >> 6, lane = t & 63;
    int m = lane & 15, q4 = lane >> 4;
    floatx4 acc0[3], acc1[3];
#pragma unroll
    for (int ct = 0; ct < 3; ct++) { acc0[ct] = (floatx4)0.0f; acc1[ct] = (floatx4)0.0f; }
#pragma unroll
    for (int kt = 0; kt < 4; kt++) {
        int kb = kt * 32 + q4 * 8;
        short8 a10 = *(const short8*)&lA1[w * 32 + m][kb];
        short8 a11 = *(const short8*)&lA1[w * 32 + 16 + m][kb];
        short8 a20 = *(const short8*)&lA2[w * 32 + m][kb];
        short8 a21 = *(const short8*)&lA2[w * 32 + 16 + m][kb];
#pragma unroll
        for (int ct = 0; ct < 3; ct++) {
            short8 bf1 = *(const short8*)&WoT1[(ct * 16 + m) * 128 + kb];
            short8 bf2 = *(const short8*)&WoT2[(ct * 16 + m) * 128 + kb];
            acc0[ct] = __builtin_amdgcn_mfma_f32_16x16x32_bf16(a10, bf1, acc0[ct], 0, 0, 0);
            acc0[ct] = __builtin_amdgcn_mfma_f32_16x16x32_bf16(a20, bf1, acc0[ct], 0, 0, 0);
            acc0[ct] = __builtin_amdgcn_mfma_f32_16x16x32_bf16(a10, bf2, acc0[ct], 0, 0, 0);
            acc1[ct] = __builtin_amdgcn_mfma_f32_16x16x32_bf16(a11, bf1, acc1[ct], 0, 0, 0);
            acc1[ct] = __builtin_amdgcn_mfma_f32_16x16x32_bf16(a21, bf1, acc1[ct], 0, 0, 0);
            acc1[ct] = __builtin_amdgcn_mfma_f32_16x16x32_bf16(a11, bf2, acc1[ct], 0, 0, 0);
        }
    }
    __syncthreads();                           // done reading lA1/lA2
    float* stage = (float*)&lA1[0][0];         // 128*40 fp32 = 20.5 KB (fits)
#pragma unroll
    for (int ct = 0; ct < 3; ct++) {
        int col = ct * 16 + m;
        if (col < 40) {
            float bb = lb[col];
#pragma unroll
            for (int r = 0; r < 4; r++) {
                stage[(w * 32 + q4 * 4 + r) * 40 + col] = acc0[ct][r] + bb;
                stage[(w * 32 + 16 + q4 * 4 + r) * 40 + col] = acc1[ct][r] + bb;
            }
        }
    }
    __syncthreads();
    int rowsLeft = n - row0; if (rowsLeft > 128) rowsLeft = 128;
    int nf4 = rowsLeft * 10;                   // 40 floats/row = 10 float4
    const float4* st4 = (const float4*)stage;
    float4* outp = (float4*)(out + (size_t)row0 * 40);
    for (int i = t; i < nf4; i += 256) outp[i] = st4[i];
}

// ---------------- launch ----------------
extern "C" void kernel_launch(void* const* d_in, const int* in_sizes, int n_in,
                              void* d_out, int out_size, void* d_ws, size_t ws_size,
                              hipStream_t stream) {
    const float* x      = (const float*)d_in[0];
    const int*   ei     = (const int*)d_in[1];
    const float* W1     = (const float*)d_in[2];
    const float* a_src1 = (const float*)d_in[3];
    const float* a_dst1 = (const float*)d_in[4];
    const float* b1     = (const float*)d_in[5];
    const float* W2     = (const float*)d_in[6];
    const float* a_src2 = (const float*)d_in[7];
    const float* a_dst2 = (const float*)d_in[8];
    const float* b2     = (const float*)d_in[9];
    const float* gamma  = (const float*)d_in[10];
    const float* beta   = (const float*)d_in[11];
    const float* Wout   = (const float*)d_in[12];
    const float* bout   = (const float*)d_in[13];
    float* out = (float*)d_out;

    char* p = (char*)d_ws;
    auto alloc = [&](size_t bytes) -> void* {
        void* r = (void*)p;
        p += (bytes + 255) & ~(size_t)255;
        return r;
    };
    unsigned short* hB    = (unsigned short*)alloc((size_t)NNODES * 128 * 2);
    unsigned short* haggB = (unsigned short*)alloc((size_t)NNODES * 128 * 2);
    float* es     = (float*)alloc((size_t)NNODES * 4);
    float* ed     = (float*)alloc((size_t)NNODES * 4);
    int*   pairs  = (int*)alloc((size_t)NBUCK * CAP * 4);   // 12.8 MB padded
    int*   srcs   = (int*)alloc((size_t)NBUCK * CAP * 4);   // 12.8 MB padded
    int2*  rowse  = (int2*)alloc((size_t)NNODES * 8);
    int*   bcur   = (int*)alloc(800 * 4);
    float* gpart  = (float*)alloc(2 * NSLOT * 256 * 4);     // 32 KB BN partials
    unsigned short* WT1  = (unsigned short*)alloc(128 * 128 * 2);
    unsigned short* WT2  = (unsigned short*)alloc(128 * 128 * 2);
    unsigned short* WoT1 = (unsigned short*)alloc(48 * 128 * 2);
    unsigned short* WoT2 = (unsigned short*)alloc(48 * 128 * 2);
    int*   flag   = (int*)alloc(4);

    float* part1 = gpart;
    float* part2 = gpart + NSLOT * 256;

    k_prep<<<64, 256, 0, stream>>>(W1, W2, Wout, WT1, WT2, WoT1, WoT2,
                                   ei, flag, bcur, gpart);
    k_bscatter<<<NBLK_E, 256, 0, stream>>>(ei, flag, bcur, pairs);
    k_bsort<<<NBUCK, 256, 0, stream>>>(pairs, bcur, rowse, srcs);

    const int GB = (NNODES + 127) / 128;          // 782 (gemm tiles)
    const int AB = NNODES / 8;                    // 12500 (8 nodes/block, exact)
    const int OB = (NNODES + 127) / 128;          // 782 (outgemm tiles)

    // ---- layer 1 ----
    k_gemm<false><<<GB, 256, 0, stream>>>(x, WT1, nullptr, nullptr, nullptr,
                                          a_src1, a_dst1, es, ed, hB, NNODES);
    k_attn<<<AB, 256, 0, stream>>>(hB, srcs, rowse, es, ed, b1, haggB, part1, NNODES);

    // ---- layer 2 (BN+ELU finalized+fused in A-staging, stats from part1) ----
    k_gemm<true><<<GB, 256, 0, stream>>>(haggB, WT2, part1, gamma, beta,
                                         a_src2, a_dst2, es, ed, hB, NNODES);
    k_attn<<<AB, 256, 0, stream>>>(hB, srcs, rowse, es, ed, b2, haggB, part2, NNODES);

    // ---- head (MFMA, BN stats from part2) ----
    k_outgemm<<<OB, 256, 0, stream>>>(haggB, part2, gamma, beta, WoT1, WoT2,
                                      bout, out, NNODES);

    (void)in_sizes; (void)n_in; (void)out_size; (void)ws_size;
}